// Round 23
// baseline (95.256 us; speedup 1.0000x reference)
//
#include <hip/hip_runtime.h>
#include <hip/hip_bf16.h>

// Problem constants
#define BATCH  8
#define SEQ    2048
#define DMODEL 1024
#define DHEAD  128

typedef __attribute__((ext_vector_type(4))) float f32x4;
typedef __attribute__((ext_vector_type(4))) float f4;
typedef _Float16 f16;
typedef __attribute__((ext_vector_type(8))) _Float16 f16x8;
typedef __attribute__((ext_vector_type(8))) __bf16 bf16x8;
typedef __attribute__((ext_vector_type(16))) unsigned short u16x16;

__device__ __forceinline__ unsigned short f2bf(float f) {
    unsigned u = __builtin_bit_cast(unsigned, f);
    u += 0x7fffu + ((u >> 16) & 1u);   // round-to-nearest-even
    return (unsigned short)(u >> 16);
}

#if __has_builtin(__builtin_amdgcn_exp2f)
#define EXP2(x) __builtin_amdgcn_exp2f(x)
#else
#define EXP2(x) exp2f(x)
#endif

__device__ __forceinline__ float fast_rcp(float x) {
#if __has_builtin(__builtin_amdgcn_rcpf)
    return __builtin_amdgcn_rcpf(x);
#else
    return 1.0f / x;
#endif
}

// ---------------------------------------------------------------------------
// Kernel 0: pre-split W into fragment-linear layout (ONCE).
// Wsp: [mat][ks][hi][row][8] f16, mat: 0=Qh 1=Ql 2=Kh 3=Kl 4=Vh.
// ---------------------------------------------------------------------------
__global__ __launch_bounds__(256) void wsplit_kernel(
    const float* __restrict__ WQ, const float* __restrict__ WK,
    const float* __restrict__ WV, f16* __restrict__ Wsp)
{
    const int gid = blockIdx.x * 256 + threadIdx.x;   // 0..81919
    const int row = gid & 127;
    const int hi  = (gid >> 7) & 3;
    const int ks  = (gid >> 9) & 31;
    const int mat = gid >> 14;                        // 0..4
    const float* W = (mat < 2) ? WQ : (mat < 4) ? WK : WV;
    const float* src = W + (size_t)row * DMODEL + ks * 32 + hi * 8;
    f4 v0 = *(const f4*)src, v1 = *(const f4*)(src + 4);
    const bool lopart = (mat == 1 || mat == 3);
    f16x8 o;
    #pragma unroll
    for (int j = 0; j < 4; ++j) {
        f16 h0 = (f16)v0[j], h1 = (f16)v1[j];
        o[j]     = lopart ? (f16)(v0[j] - (float)h0) : h0;
        o[j + 4] = lopart ? (f16)(v1[j] - (float)h1) : h1;
    }
    *reinterpret_cast<f16x8*>(Wsp + (size_t)gid * 8) = o;
}

// ---------------------------------------------------------------------------
// Kernel 1: FUSED projections — BK=64 (r20-exact, best measured 46.6us).
// ---------------------------------------------------------------------------
__global__ __launch_bounds__(256, 2) void proj_kernel(
    const float* __restrict__ x, const f16* __restrict__ Wsp,
    f16* __restrict__ Qh, f16* __restrict__ Ql,
    f16* __restrict__ Kh, f16* __restrict__ Kl,
    unsigned short* __restrict__ Vtb)
{
    __shared__ f16 Ax[2][2][4][8][17][8];   // [buf][h/l][rb][chunk8][ro17][8] 34.8KB

    const int tid  = threadIdx.x;
    const int lane = tid & 63;
    const int w    = tid >> 6;              // 0..3
    const int lo   = lane & 15;
    const int hi   = lane >> 4;
    const int m0   = blockIdx.x * 64;
    const int bn   = blockIdx.y;            // 0/1: col half
    const int fi   = hi * 128 + bn * 64 + w * 16 + lo;

    const int xrow = tid >> 2;              // 0..63
    const int xg   = tid & 3;               // chunk pair {xg, xg+4}
    const int xrb  = xrow >> 4, xro = xrow & 15;

    f32x4 accQ[4] = {}, accK[4] = {}, accV[4] = {};

    const float* xbase = x + (size_t)(m0 + xrow) * DMODEL + xg * 8;
    const f16*   wbase = Wsp + (size_t)fi * 8;

    f4 rx0, rx1, rx2, rx3;
    auto loadX = [&](int ks2) {
        const float* p = xbase + ks2 * 64;
        rx0 = *(const f4*)(p);
        rx1 = *(const f4*)(p + 4);
        rx2 = *(const f4*)(p + 32);
        rx3 = *(const f4*)(p + 36);
    };
    auto cvt8 = [](f4 v0, f4 v1, f16x8& h8, f16x8& l8) {
        #pragma unroll
        for (int j = 0; j < 4; ++j) {
            f16 h0 = (f16)v0[j]; h8[j]     = h0; l8[j]     = (f16)(v0[j] - (float)h0);
            f16 h1 = (f16)v1[j]; h8[j + 4] = h1; l8[j + 4] = (f16)(v1[j] - (float)h1);
        }
    };
    auto writeX = [&](int buf) {
        f16x8 h8, l8;
        cvt8(rx0, rx1, h8, l8);
        *reinterpret_cast<f16x8*>(&Ax[buf][0][xrb][xg][xro][0]) = h8;
        *reinterpret_cast<f16x8*>(&Ax[buf][1][xrb][xg][xro][0]) = l8;
        cvt8(rx2, rx3, h8, l8);
        *reinterpret_cast<f16x8*>(&Ax[buf][0][xrb][xg + 4][xro][0]) = h8;
        *reinterpret_cast<f16x8*>(&Ax[buf][1][xrb][xg + 4][xro][0]) = l8;
    };

    loadX(0);
    writeX(0);
    __syncthreads();

    for (int ks2 = 0; ks2 < 16; ++ks2) {
        const int cur = ks2 & 1;
        if (ks2 < 15) loadX(ks2 + 1);

        f16x8 W10[10];
        #pragma unroll
        for (int kk = 0; kk < 2; ++kk)
            #pragma unroll
            for (int m = 0; m < 5; ++m)
                W10[kk * 5 + m] = *reinterpret_cast<const f16x8*>(
                    wbase + (size_t)(m * 32 + ks2 * 2 + kk) * 4096);

        #pragma unroll
        for (int kk = 0; kk < 2; ++kk) {
            const f16x8* Wc = &W10[kk * 5];
            #pragma unroll
            for (int rb = 0; rb < 4; ++rb) {
                f16x8 ah = *reinterpret_cast<const f16x8*>(&Ax[cur][0][rb][kk * 4 + hi][lo][0]);
                f16x8 al = *reinterpret_cast<const f16x8*>(&Ax[cur][1][rb][kk * 4 + hi][lo][0]);
                accQ[rb] = __builtin_amdgcn_mfma_f32_16x16x32_f16(ah, Wc[0], accQ[rb], 0, 0, 0);
                accQ[rb] = __builtin_amdgcn_mfma_f32_16x16x32_f16(ah, Wc[1], accQ[rb], 0, 0, 0);
                accQ[rb] = __builtin_amdgcn_mfma_f32_16x16x32_f16(al, Wc[0], accQ[rb], 0, 0, 0);
                accK[rb] = __builtin_amdgcn_mfma_f32_16x16x32_f16(ah, Wc[2], accK[rb], 0, 0, 0);
                accK[rb] = __builtin_amdgcn_mfma_f32_16x16x32_f16(ah, Wc[3], accK[rb], 0, 0, 0);
                accK[rb] = __builtin_amdgcn_mfma_f32_16x16x32_f16(al, Wc[2], accK[rb], 0, 0, 0);
                accV[rb] = __builtin_amdgcn_mfma_f32_16x16x32_f16(ah, Wc[4], accV[rb], 0, 0, 0);
            }
        }
        if (ks2 < 15) writeX(cur ^ 1);
        __syncthreads();
    }

    // epilogue: D layout col = lane&15, row = (lane>>4)*4 + r
    #pragma unroll
    for (int rb = 0; rb < 4; ++rb)
        #pragma unroll
        for (int r = 0; r < 4; ++r) {
            const int m = m0 + rb * 16 + hi * 4 + r;
            const int n = bn * 64 + w * 16 + lo;
            const size_t idx = (size_t)m * DHEAD + n;
            float vq = accQ[rb][r];
            f16 hq = (f16)vq;
            Qh[idx] = hq; Ql[idx] = (f16)(vq - (float)hq);
            float vk = accK[rb][r];
            f16 hk = (f16)vk;
            Kh[idx] = hk; Kl[idx] = (f16)(vk - (float)hk);
            const int bb = m >> 11, l = m & 2047;
            Vtb[((size_t)bb * DHEAD + n) * SEQ + l] = f2bf(accV[rb][r]);
        }
}

// ---------------------------------------------------------------------------
// Kernel 2: causal tanh-capped attention, rescale-free flash, NZ-way KEY-SPLIT.
// P = exp(30*tanh(s)-30) = exp2(-86.5617/(exp2(0.2551*s_raw)+1)) in [8.8e-27,1]
// Insight (r22 pm): the 8-wave block's wk halves consumed DISJOINT LDS halves
// -> zero reuse loss shrinking to 256-thr blocks + 32-key tiles. LDS 32.1KB
// -> 4 blocks/CU (attn was latency-bound at 1-2 blocks/CU, MfmaUtil 10%).
// Single-buffered, 2 barriers/iter, reg prefetch distance = 1 iter.
// NZ = gridDim.z key-split (linear partials); waves own disjoint q-rows ->
// NO cross-wave merge at all. Heavy-first qs.
// ---------------------------------------------------------------------------
#define PART_STRIDE 8256   // 64*128 + 64 floats
__global__ __launch_bounds__(256) void attn_kernel(
    const f16* __restrict__ Qh, const f16* __restrict__ Ql,
    const f16* __restrict__ Kh, const f16* __restrict__ Kl,
    const unsigned short* __restrict__ Vtb, const int* __restrict__ mask,
    float* __restrict__ part)
{
    __shared__ f16 Khs[32][136];                //  8704 B
    __shared__ f16 Kls[32][136];                //  8704 B
    __shared__ unsigned short Vs[128][40];      // 10240 B
    __shared__ int Ms[32];                      //   128 B
    __shared__ unsigned short Plds[4][16][40];  //  5120 B (total 32.1 KB)

    const int tid  = threadIdx.x;
    const int lane = tid & 63;
    const int w    = tid >> 6;                  // 0..3 (q-row quadrant)
    const int lo   = lane & 15;
    const int hi   = lane >> 4;
    const int b    = blockIdx.x;
    const int qs   = 31 - (int)blockIdx.y;      // heavy blocks first
    const int z    = blockIdx.z;
    const int NZ   = gridDim.z;
    const int qrow = qs * 64 + w * 16;
    const int ntiles = qs * 2 + 2;              // 32-key tiles

    const float c2p = 0.25506061907448296f;     // (2*log2e)/sqrt(128)
    const float c1  = -86.561702453337804f;     // -60*log2e

    f16x8 qh[4], ql[4];
    {
        const size_t off = ((size_t)(b * SEQ + qrow + lo)) * DHEAD + hi * 8;
        #pragma unroll
        for (int c = 0; c < 4; ++c) {
            qh[c] = *reinterpret_cast<const f16x8*>(Qh + off + c * 32);
            ql[c] = *reinterpret_cast<const f16x8*>(Ql + off + c * 32);
        }
    }

    const int krow = tid >> 3;                  // 0..31
    const int kcol = (tid & 7) * 16;            // 0..112
    const int vrow = tid >> 1;                  // 0..127
    const int vcol = (tid & 1) * 16;            // 0,16

    f16x8  rKh0, rKh1, rKl0, rKl1;
    u16x16 rV;
    int    rM = 0;

    auto load_tile = [&](int kb) {
        const size_t koff = ((size_t)(b * SEQ + kb + krow)) * DHEAD + kcol;
        rKh0 = *reinterpret_cast<const f16x8*>(Kh + koff);
        rKh1 = *reinterpret_cast<const f16x8*>(Kh + koff + 8);
        rKl0 = *reinterpret_cast<const f16x8*>(Kl + koff);
        rKl1 = *reinterpret_cast<const f16x8*>(Kl + koff + 8);
        rV   = *reinterpret_cast<const u16x16*>(Vtb + ((size_t)b * DHEAD + vrow) * SEQ + kb + vcol);
        if (tid < 32) rM = mask[b * SEQ + kb + tid];
    };
    auto write_tile = [&]() {
        *reinterpret_cast<f16x8*>(&Khs[krow][kcol])     = rKh0;
        *reinterpret_cast<f16x8*>(&Khs[krow][kcol + 8]) = rKh1;
        *reinterpret_cast<f16x8*>(&Kls[krow][kcol])     = rKl0;
        *reinterpret_cast<f16x8*>(&Kls[krow][kcol + 8]) = rKl1;
        *reinterpret_cast<u16x16*>(&Vs[vrow][vcol]) = rV;
        if (tid < 32) Ms[tid] = rM;
    };

    // prologue: tile z -> LDS; preload tile z+NZ into regs
    load_tile(z * 32);
    write_tile();
    if (z + NZ < ntiles) load_tile((z + NZ) * 32);
    __syncthreads();

    f32x4 acc[8] = {};
    float rs[4] = {0.f, 0.f, 0.f, 0.f};

    for (int it = z; it < ntiles; it += NZ) {
        const int kb = it * 32;
        if (kb <= qrow + 15) {
            #pragma unroll
            for (int h = 0; h < 2; ++h) {
                f32x4 s = {};
                #pragma unroll
                for (int c = 0; c < 4; ++c) {
                    f16x8 fkh = *reinterpret_cast<const f16x8*>(&Khs[h * 16 + lo][c * 32 + hi * 8]);
                    f16x8 fkl = *reinterpret_cast<const f16x8*>(&Kls[h * 16 + lo][c * 32 + hi * 8]);
                    s = __builtin_amdgcn_mfma_f32_16x16x32_f16(qh[c], fkh, s, 0, 0, 0);
                    s = __builtin_amdgcn_mfma_f32_16x16x32_f16(qh[c], fkl, s, 0, 0, 0);
                    s = __builtin_amdgcn_mfma_f32_16x16x32_f16(ql[c], fkh, s, 0, 0, 0);
                }
                const int key = kb + h * 16 + lo;
                const int mk  = Ms[h * 16 + lo];
                #pragma unroll
                for (int r = 0; r < 4; ++r) {
                    const int q = qrow + hi * 4 + r;
                    float t = EXP2(s[r] * c2p);               // e^{2s} (inf ok)
                    float p = EXP2(c1 * fast_rcp(t + 1.0f));
                    p = (key <= q && mk != 0) ? p : 0.0f;     // causal + padding
                    rs[r] += p;
                    Plds[w][hi * 4 + r][h * 16 + lo] = f2bf(p);
                }
            }
            bf16x8 pa = *reinterpret_cast<const bf16x8*>(&Plds[w][lo][hi * 8]);
            #pragma unroll
            for (int dt = 0; dt < 8; ++dt) {
                bf16x8 vf = *reinterpret_cast<const bf16x8*>(&Vs[dt * 16 + lo][hi * 8]);
                acc[dt] = __builtin_amdgcn_mfma_f32_16x16x32_bf16(pa, vf, acc[dt], 0, 0, 0);
            }
        }

        __syncthreads();   // all waves done READING current tile
        if (it + NZ < ntiles) {
            write_tile();                          // regs hold tile it+NZ
            if (it + 2 * NZ < ntiles) load_tile((it + 2 * NZ) * 32);
        }
        __syncthreads();   // new tile visible
    }

    // epilogue: waves own disjoint q-rows -> direct partial write, no merge.
    float rsum[4];
    #pragma unroll
    for (int r = 0; r < 4; ++r) {
        float v = rs[r];
        v += __shfl_xor(v, 1);
        v += __shfl_xor(v, 2);
        v += __shfl_xor(v, 4);
        v += __shfl_xor(v, 8);
        rsum[r] = v;
    }
    float* P = part + (((size_t)b * 32 + qs) * NZ + z) * PART_STRIDE;
    #pragma unroll
    for (int dt = 0; dt < 8; ++dt)
        #pragma unroll
        for (int r = 0; r < 4; ++r)
            P[(w * 16 + hi * 4 + r) * 128 + dt * 16 + lo] = acc[dt][r];
    if (lo == 0)
        #pragma unroll
        for (int r = 0; r < 4; ++r)
            P[8192 + w * 16 + hi * 4 + r] = rsum[r];
}

// ---------------------------------------------------------------------------
// Kernel 3: merge the NZ key-split partials and normalize.
// out[b,q,:] = (sum_z A_z) / (sum_z rs_z)
// ---------------------------------------------------------------------------
__global__ __launch_bounds__(256) void merge_kernel(
    const float* __restrict__ part, float* __restrict__ out, int NZ)
{
    const int gid = blockIdx.x * 256 + threadIdx.x;   // 0..524287
    const int col = (gid & 31) * 4;
    const int q   = gid >> 5;                         // 0..16383
    const int b   = q >> 11, l = q & 2047;
    const int qs  = l >> 6, row = l & 63;
    const float* P0 = part + (((size_t)b * 32 + qs) * NZ) * PART_STRIDE;
    f4 a = {};
    float den = 0.f;
    for (int zz = 0; zz < NZ; ++zz) {
        const float* P = P0 + (size_t)zz * PART_STRIDE;
        f4 av = *(const f4*)(P + row * 128 + col);
        #pragma unroll
        for (int j = 0; j < 4; ++j) a[j] += av[j];
        den += P[8192 + row];
    }
    float inv = fast_rcp(den);
    f4 o;
    #pragma unroll
    for (int j = 0; j < 4; ++j) o[j] = a[j] * inv;
    *(f4*)(out + (size_t)q * 128 + col) = o;
}

extern "C" void kernel_launch(void* const* d_in, const int* in_sizes, int n_in,
                              void* d_out, int out_size, void* d_ws, size_t ws_size,
                              hipStream_t stream) {
    const float* x   = (const float*)d_in[0];
    const int*   msk = (const int*)d_in[1];
    const float* WQ  = (const float*)d_in[2];
    const float* WK  = (const float*)d_in[3];
    const float* WV  = (const float*)d_in[4];
    float* out = (float*)d_out;

    // ws: Qh|Ql|Kh|Kl (f16) | Vt (bf16) 20MB | Wsp 1.31MB | part (NZ slots)
    const size_t NE = (size_t)BATCH * SEQ * DHEAD;
    f16* Qh = (f16*)d_ws;
    f16* Ql = Qh + NE;
    f16* Kh = Ql + NE;
    f16* Kl = Kh + NE;
    unsigned short* Vtb = (unsigned short*)(Kl + NE);
    f16* Wsp = (f16*)(Vtb + NE);
    float* part = (float*)(Wsp + (size_t)5 * 32 * 4096);

    const size_t base = (size_t)5 * NE * 2 + (size_t)5 * 32 * 4096 * 2;
    const size_t part4 = (size_t)BATCH * 32 * 4 * PART_STRIDE * 4;
    const int NZ = (ws_size >= base + part4) ? 4 : 2;   // deterministic

    wsplit_kernel<<<320, 256, 0, stream>>>(WQ, WK, WV, Wsp);
    proj_kernel<<<dim3(BATCH * SEQ / 64, 2), 256, 0, stream>>>(x, Wsp, Qh, Ql, Kh, Kl, Vtb);
    attn_kernel<<<dim3(BATCH, 32, NZ), 256, 0, stream>>>(Qh, Ql, Kh, Kl, Vtb, msk, part);
    merge_kernel<<<2048, 256, 0, stream>>>(part, out, NZ);
}

// Round 24
// 86.173 us; speedup vs baseline: 1.1054x; 1.1054x over previous
//
#include <hip/hip_runtime.h>
#include <hip/hip_bf16.h>

// Problem constants
#define BATCH  8
#define SEQ    2048
#define DMODEL 1024
#define DHEAD  128

typedef __attribute__((ext_vector_type(4))) float f32x4;
typedef __attribute__((ext_vector_type(4))) float f4;
typedef _Float16 f16;
typedef __attribute__((ext_vector_type(8))) _Float16 f16x8;
typedef __attribute__((ext_vector_type(8))) __bf16 bf16x8;
typedef __attribute__((ext_vector_type(16))) unsigned short u16x16;

__device__ __forceinline__ unsigned short f2bf(float f) {
    unsigned u = __builtin_bit_cast(unsigned, f);
    u += 0x7fffu + ((u >> 16) & 1u);   // round-to-nearest-even
    return (unsigned short)(u >> 16);
}

#if __has_builtin(__builtin_amdgcn_exp2f)
#define EXP2(x) __builtin_amdgcn_exp2f(x)
#else
#define EXP2(x) exp2f(x)
#endif

__device__ __forceinline__ float fast_rcp(float x) {
#if __has_builtin(__builtin_amdgcn_rcpf)
    return __builtin_amdgcn_rcpf(x);
#else
    return 1.0f / x;
#endif
}

// ---------------------------------------------------------------------------
// Kernel 0: pre-split W into fragment-linear layout (ONCE).
// Wsp: [mat][ks][hi][row][8] f16, mat: 0=Qh 1=Ql 2=Kh 3=Kl 4=Vh (ks = 32-col
// K-tiles; proj BK=64 reads two consecutive ks per step).
// ---------------------------------------------------------------------------
__global__ __launch_bounds__(256) void wsplit_kernel(
    const float* __restrict__ WQ, const float* __restrict__ WK,
    const float* __restrict__ WV, f16* __restrict__ Wsp)
{
    const int gid = blockIdx.x * 256 + threadIdx.x;   // 0..81919
    const int row = gid & 127;
    const int hi  = (gid >> 7) & 3;
    const int ks  = (gid >> 9) & 31;
    const int mat = gid >> 14;                        // 0..4
    const float* W = (mat < 2) ? WQ : (mat < 4) ? WK : WV;
    const float* src = W + (size_t)row * DMODEL + ks * 32 + hi * 8;
    f4 v0 = *(const f4*)src, v1 = *(const f4*)(src + 4);
    const bool lopart = (mat == 1 || mat == 3);
    f16x8 o;
    #pragma unroll
    for (int j = 0; j < 4; ++j) {
        f16 h0 = (f16)v0[j], h1 = (f16)v1[j];
        o[j]     = lopart ? (f16)(v0[j] - (float)h0) : h0;
        o[j + 4] = lopart ? (f16)(v1[j] - (float)h1) : h1;
    }
    *reinterpret_cast<f16x8*>(Wsp + (size_t)gid * 8) = o;
}

// ---------------------------------------------------------------------------
// Kernel 1: FUSED projections — BK=64 (best measured: 46.6us, r20).
// Per step: x 64x64 f32 tile staged hi/lo in LDS (16 f32/thread, write
// distance = full step); 10 W fragments (5 mats x 2 K-halves) direct from
// L2-resident pre-split Wsp; 56 MFMA/wave. LDS 34.8KB, 2 blocks/CU.
// Q,K split-f16 (f32-grade scores: tanh transition |s|~3 vs raw std ~1024);
// V single MFMA -> bf16 store (range: P in [8.8e-27,1] pairs with V).
// ---------------------------------------------------------------------------
__global__ __launch_bounds__(256, 2) void proj_kernel(
    const float* __restrict__ x, const f16* __restrict__ Wsp,
    f16* __restrict__ Qh, f16* __restrict__ Ql,
    f16* __restrict__ Kh, f16* __restrict__ Kl,
    unsigned short* __restrict__ Vtb)
{
    __shared__ f16 Ax[2][2][4][8][17][8];   // [buf][h/l][rb][chunk8][ro17][8] 34.8KB

    const int tid  = threadIdx.x;
    const int lane = tid & 63;
    const int w    = tid >> 6;              // 0..3
    const int lo   = lane & 15;
    const int hi   = lane >> 4;
    const int m0   = blockIdx.x * 64;
    const int bn   = blockIdx.y;            // 0/1: col half
    const int fi   = hi * 128 + bn * 64 + w * 16 + lo;

    const int xrow = tid >> 2;              // 0..63
    const int xg   = tid & 3;               // chunk pair {xg, xg+4}
    const int xrb  = xrow >> 4, xro = xrow & 15;

    f32x4 accQ[4] = {}, accK[4] = {}, accV[4] = {};

    const float* xbase = x + (size_t)(m0 + xrow) * DMODEL + xg * 8;
    const f16*   wbase = Wsp + (size_t)fi * 8;

    f4 rx0, rx1, rx2, rx3;
    auto loadX = [&](int ks2) {             // 64-col tile ks2: chunks xg, xg+4
        const float* p = xbase + ks2 * 64;
        rx0 = *(const f4*)(p);
        rx1 = *(const f4*)(p + 4);
        rx2 = *(const f4*)(p + 32);
        rx3 = *(const f4*)(p + 36);
    };
    auto cvt8 = [](f4 v0, f4 v1, f16x8& h8, f16x8& l8) {
        #pragma unroll
        for (int j = 0; j < 4; ++j) {
            f16 h0 = (f16)v0[j]; h8[j]     = h0; l8[j]     = (f16)(v0[j] - (float)h0);
            f16 h1 = (f16)v1[j]; h8[j + 4] = h1; l8[j + 4] = (f16)(v1[j] - (float)h1);
        }
    };
    auto writeX = [&](int buf) {
        f16x8 h8, l8;
        cvt8(rx0, rx1, h8, l8);
        *reinterpret_cast<f16x8*>(&Ax[buf][0][xrb][xg][xro][0]) = h8;
        *reinterpret_cast<f16x8*>(&Ax[buf][1][xrb][xg][xro][0]) = l8;
        cvt8(rx2, rx3, h8, l8);
        *reinterpret_cast<f16x8*>(&Ax[buf][0][xrb][xg + 4][xro][0]) = h8;
        *reinterpret_cast<f16x8*>(&Ax[buf][1][xrb][xg + 4][xro][0]) = l8;
    };

    loadX(0);
    writeX(0);
    __syncthreads();

    for (int ks2 = 0; ks2 < 16; ++ks2) {
        const int cur = ks2 & 1;
        if (ks2 < 15) loadX(ks2 + 1);       // HBM latency hides under this step

        // 10 W fragments for this 64-col K-slab (L2-resident)
        f16x8 W10[10];
        #pragma unroll
        for (int kk = 0; kk < 2; ++kk)
            #pragma unroll
            for (int m = 0; m < 5; ++m)
                W10[kk * 5 + m] = *reinterpret_cast<const f16x8*>(
                    wbase + (size_t)(m * 32 + ks2 * 2 + kk) * 4096);

        #pragma unroll
        for (int kk = 0; kk < 2; ++kk) {
            const f16x8* Wc = &W10[kk * 5];
            #pragma unroll
            for (int rb = 0; rb < 4; ++rb) {
                f16x8 ah = *reinterpret_cast<const f16x8*>(&Ax[cur][0][rb][kk * 4 + hi][lo][0]);
                f16x8 al = *reinterpret_cast<const f16x8*>(&Ax[cur][1][rb][kk * 4 + hi][lo][0]);
                accQ[rb] = __builtin_amdgcn_mfma_f32_16x16x32_f16(ah, Wc[0], accQ[rb], 0, 0, 0);
                accQ[rb] = __builtin_amdgcn_mfma_f32_16x16x32_f16(ah, Wc[1], accQ[rb], 0, 0, 0);
                accQ[rb] = __builtin_amdgcn_mfma_f32_16x16x32_f16(al, Wc[0], accQ[rb], 0, 0, 0);
                accK[rb] = __builtin_amdgcn_mfma_f32_16x16x32_f16(ah, Wc[2], accK[rb], 0, 0, 0);
                accK[rb] = __builtin_amdgcn_mfma_f32_16x16x32_f16(ah, Wc[3], accK[rb], 0, 0, 0);
                accK[rb] = __builtin_amdgcn_mfma_f32_16x16x32_f16(al, Wc[2], accK[rb], 0, 0, 0);
                accV[rb] = __builtin_amdgcn_mfma_f32_16x16x32_f16(ah, Wc[4], accV[rb], 0, 0, 0);
            }
        }
        if (ks2 < 15) writeX(cur ^ 1);
        __syncthreads();
    }

    // epilogue: D layout col = lane&15, row = (lane>>4)*4 + r
    #pragma unroll
    for (int rb = 0; rb < 4; ++rb)
        #pragma unroll
        for (int r = 0; r < 4; ++r) {
            const int m = m0 + rb * 16 + hi * 4 + r;
            const int n = bn * 64 + w * 16 + lo;
            const size_t idx = (size_t)m * DHEAD + n;
            float vq = accQ[rb][r];
            f16 hq = (f16)vq;
            Qh[idx] = hq; Ql[idx] = (f16)(vq - (float)hq);
            float vk = accK[rb][r];
            f16 hk = (f16)vk;
            Kh[idx] = hk; Kl[idx] = (f16)(vk - (float)hk);
            const int bb = m >> 11, l = m & 2047;
            Vtb[((size_t)bb * DHEAD + n) * SEQ + l] = f2bf(accV[rb][r]);
        }
}

// ---------------------------------------------------------------------------
// Kernel 2: causal tanh-capped attention, rescale-free flash, KEY-SPLIT
// (r13 structure — best measured ~30-33us; r18/r22/r23 variants all
// regressed: 64-key double-buffered tiles at 1 barrier/iter is the
// empirical optimum of the interval-cost trade).
// P = exp(30*tanh(s)-30) = exp2(-86.5617/(exp2(0.2551*s_raw)+1)) in [8.8e-27,1]
// ---------------------------------------------------------------------------
#define PART_STRIDE 8256   // 64*128 + 64 floats
__global__ __launch_bounds__(512) void attn_kernel(
    const f16* __restrict__ Qh, const f16* __restrict__ Ql,
    const f16* __restrict__ Kh, const f16* __restrict__ Kl,
    const unsigned short* __restrict__ Vtb, const int* __restrict__ mask,
    float* __restrict__ part)
{
    __shared__ f16 Khs[2][64][136];
    __shared__ f16 Kls[2][64][136];
    __shared__ unsigned short Vs[2][128][72];
    __shared__ int Ms[2][64];
    __shared__ unsigned short Plds[8][16][40];

    const int tid  = threadIdx.x;
    const int lane = tid & 63;
    const int w    = tid >> 6;                  // 0..7
    const int lo   = lane & 15;
    const int hi   = lane >> 4;
    const int wq   = w & 3;
    const int wk   = w >> 2;
    const int b    = blockIdx.x;
    const int qs   = 31 - (int)blockIdx.y;      // heavy blocks first
    const int z    = blockIdx.z;                // key-split half
    const int qrow = qs * 64 + wq * 16;

    const float c2p = 0.25506061907448296f;     // (2*log2e)/sqrt(128)
    const float c1  = -86.561702453337804f;     // -60*log2e

    f16x8 qh[4], ql[4];
    {
        const size_t off = ((size_t)(b * SEQ + qrow + lo)) * DHEAD + hi * 8;
        #pragma unroll
        for (int c = 0; c < 4; ++c) {
            qh[c] = *reinterpret_cast<const f16x8*>(Qh + off + c * 32);
            ql[c] = *reinterpret_cast<const f16x8*>(Ql + off + c * 32);
        }
    }

    const int krow = tid >> 3;                  // 0..63
    const int kcol = (tid & 7) * 16;            // 0..112
    const int vrow = tid >> 2;                  // 0..127
    const int vcol = (tid & 3) * 16;            // 0,16,32,48

    f16x8  rKh0, rKh1, rKl0, rKl1;
    u16x16 rV;
    int    rM = 0;

    auto load_tile = [&](int kb) {
        const size_t koff = ((size_t)(b * SEQ + kb + krow)) * DHEAD + kcol;
        rKh0 = *reinterpret_cast<const f16x8*>(Kh + koff);
        rKh1 = *reinterpret_cast<const f16x8*>(Kh + koff + 8);
        rKl0 = *reinterpret_cast<const f16x8*>(Kl + koff);
        rKl1 = *reinterpret_cast<const f16x8*>(Kl + koff + 8);
        rV   = *reinterpret_cast<const u16x16*>(Vtb + ((size_t)b * DHEAD + vrow) * SEQ + kb + vcol);
        if (tid < 64) rM = mask[b * SEQ + kb + tid];
    };
    auto write_tile = [&](int buf) {
        *reinterpret_cast<f16x8*>(&Khs[buf][krow][kcol])     = rKh0;
        *reinterpret_cast<f16x8*>(&Khs[buf][krow][kcol + 8]) = rKh1;
        *reinterpret_cast<f16x8*>(&Kls[buf][krow][kcol])     = rKl0;
        *reinterpret_cast<f16x8*>(&Kls[buf][krow][kcol + 8]) = rKl1;
        *reinterpret_cast<u16x16*>(&Vs[buf][vrow][vcol]) = rV;
        if (tid < 64) Ms[buf][tid] = rM;
    };

    load_tile(z * 64);
    write_tile(0);
    __syncthreads();

    f32x4 acc[8] = {};
    float rs[4] = {0.f, 0.f, 0.f, 0.f};

    int cnt = 0;
    for (int it = z; it <= qs; it += 2, ++cnt) {
        const int cur = cnt & 1;
        const bool havenext = (it + 2 <= qs);
        if (havenext) load_tile((it + 2) * 64);

        const int kb = it * 64 + wk * 32;
        if (kb <= qrow + 15) {
            #pragma unroll
            for (int h = 0; h < 2; ++h) {
                f32x4 s = {};
                #pragma unroll
                for (int c = 0; c < 4; ++c) {
                    f16x8 fkh = *reinterpret_cast<const f16x8*>(&Khs[cur][wk * 32 + h * 16 + lo][c * 32 + hi * 8]);
                    f16x8 fkl = *reinterpret_cast<const f16x8*>(&Kls[cur][wk * 32 + h * 16 + lo][c * 32 + hi * 8]);
                    s = __builtin_amdgcn_mfma_f32_16x16x32_f16(qh[c], fkh, s, 0, 0, 0);
                    s = __builtin_amdgcn_mfma_f32_16x16x32_f16(qh[c], fkl, s, 0, 0, 0);
                    s = __builtin_amdgcn_mfma_f32_16x16x32_f16(ql[c], fkh, s, 0, 0, 0);
                }
                const int key = kb + h * 16 + lo;
                const int mk  = Ms[cur][wk * 32 + h * 16 + lo];
                #pragma unroll
                for (int r = 0; r < 4; ++r) {
                    const int q = qrow + hi * 4 + r;
                    float t = EXP2(s[r] * c2p);               // e^{2s} (inf ok)
                    float p = EXP2(c1 * fast_rcp(t + 1.0f));
                    p = (key <= q && mk != 0) ? p : 0.0f;     // causal + padding
                    rs[r] += p;
                    Plds[w][hi * 4 + r][h * 16 + lo] = f2bf(p);
                }
            }
            bf16x8 pa = *reinterpret_cast<const bf16x8*>(&Plds[w][lo][hi * 8]);
            #pragma unroll
            for (int dt = 0; dt < 8; ++dt) {
                bf16x8 vf = *reinterpret_cast<const bf16x8*>(&Vs[cur][dt * 16 + lo][wk * 32 + hi * 8]);
                acc[dt] = __builtin_amdgcn_mfma_f32_16x16x32_bf16(pa, vf, acc[dt], 0, 0, 0);
            }
        }

        if (havenext) write_tile(cur ^ 1);
        __syncthreads();
    }

    // 2-way wk merge via LDS, then write UNNORMALIZED partials + rs sums.
    float* red = (float*)&Khs[0][0][0];
    if (wk == 1) {
        float* dst = red + ((size_t)wq * 64 + lane) * 36;
        #pragma unroll
        for (int dt = 0; dt < 8; ++dt)
            #pragma unroll
            for (int r = 0; r < 4; ++r) dst[dt * 4 + r] = acc[dt][r];
        #pragma unroll
        for (int r = 0; r < 4; ++r) dst[32 + r] = rs[r];
    }
    __syncthreads();
    if (wk == 0) {
        const float* src = red + ((size_t)wq * 64 + lane) * 36;
        #pragma unroll
        for (int dt = 0; dt < 8; ++dt)
            #pragma unroll
            for (int r = 0; r < 4; ++r) acc[dt][r] += src[dt * 4 + r];
        float rsum[4];
        #pragma unroll
        for (int r = 0; r < 4; ++r) {
            float v = rs[r] + src[32 + r];
            v += __shfl_xor(v, 1);
            v += __shfl_xor(v, 2);
            v += __shfl_xor(v, 4);
            v += __shfl_xor(v, 8);
            rsum[r] = v;
        }
        float* P = part + (((size_t)b * 32 + qs) * 2 + z) * PART_STRIDE;
        #pragma unroll
        for (int dt = 0; dt < 8; ++dt)
            #pragma unroll
            for (int r = 0; r < 4; ++r)
                P[(wq * 16 + hi * 4 + r) * 128 + dt * 16 + lo] = acc[dt][r];
        if (lo == 0)
            #pragma unroll
            for (int r = 0; r < 4; ++r)
                P[8192 + wq * 16 + hi * 4 + r] = rsum[r];
    }
}

// ---------------------------------------------------------------------------
// Kernel 3: merge the two key-split partials and normalize.
// out[b,q,:] = (A0 + A1) / (rs0 + rs1)
// ---------------------------------------------------------------------------
__global__ __launch_bounds__(256) void merge_kernel(
    const float* __restrict__ part, float* __restrict__ out)
{
    const int gid = blockIdx.x * 256 + threadIdx.x;   // 0..524287
    const int col = (gid & 31) * 4;
    const int q   = gid >> 5;                         // 0..16383
    const int b   = q >> 11, l = q & 2047;
    const int qs  = l >> 6, row = l & 63;
    const float* P0 = part + (((size_t)b * 32 + qs) * 2) * PART_STRIDE;
    const float* P1 = P0 + PART_STRIDE;
    f4 a0 = *(const f4*)(P0 + row * 128 + col);
    f4 a1 = *(const f4*)(P1 + row * 128 + col);
    float inv = fast_rcp(P0[8192 + row] + P1[8192 + row]);
    f4 o;
    #pragma unroll
    for (int j = 0; j < 4; ++j) o[j] = (a0[j] + a1[j]) * inv;
    *(f4*)(out + (size_t)q * 128 + col) = o;
}

extern "C" void kernel_launch(void* const* d_in, const int* in_sizes, int n_in,
                              void* d_out, int out_size, void* d_ws, size_t ws_size,
                              hipStream_t stream) {
    const float* x   = (const float*)d_in[0];
    const int*   msk = (const int*)d_in[1];
    const float* WQ  = (const float*)d_in[2];
    const float* WK  = (const float*)d_in[3];
    const float* WV  = (const float*)d_in[4];
    float* out = (float*)d_out;

    // ws: Qh|Ql|Kh|Kl (f16) | Vt (bf16) 20MB | Wsp 1.31MB | part 16.9MB
    const size_t NE = (size_t)BATCH * SEQ * DHEAD;
    f16* Qh = (f16*)d_ws;
    f16* Ql = Qh + NE;
    f16* Kh = Ql + NE;
    f16* Kl = Kh + NE;
    unsigned short* Vtb = (unsigned short*)(Kl + NE);
    f16* Wsp = (f16*)(Vtb + NE);
    float* part = (float*)(Wsp + (size_t)5 * 32 * 4096);

    wsplit_kernel<<<320, 256, 0, stream>>>(WQ, WK, WV, Wsp);
    proj_kernel<<<dim3(BATCH * SEQ / 64, 2), 256, 0, stream>>>(x, Wsp, Qh, Ql, Kh, Kl, Vtb);
    attn_kernel<<<dim3(BATCH, 32, 2), 512, 0, stream>>>(Qh, Ql, Kh, Kl, Vtb, msk, part);
    merge_kernel<<<2048, 256, 0, stream>>>(part, out);
}